// Round 1
// baseline (261.152 us; speedup 1.0000x reference)
//
#include <hip/hip_runtime.h>

#define BATCH 32768
#define SEQLEN 12
#define PEDS 16
#define NBLK (BATCH/PEDS)   // 2048

typedef short short8 __attribute__((ext_vector_type(8)));
typedef float f32x4 __attribute__((ext_vector_type(4)));

static __device__ __forceinline__ unsigned short f2bf(float x) {
    unsigned u = __float_as_uint(x);
    return (unsigned short)((u + 0x7FFFu + ((u >> 16) & 1u)) >> 16);  // RNE
}
static __device__ __forceinline__ float bf2f(unsigned short h) {
    return __uint_as_float(((unsigned)h) << 16);
}

// conv1 collapsed to affine form in raw positions (exact fp32):
//   s1[oc][t] = relu( sum_tap A[oc][tap]*p0[t+tap] + B[oc][tap]*p1[t+tap] + K1[oc] )
// conv2/conv3 via MFMA with full 3-product bf16 hi/lo compensation.
//
// s1 ring is 4 slots (steady-state liveness: conv2 col c reads s1 c..c+2 while
// col c+3 is written). This cuts LDS 48.7->39.5 KB -> 4 blocks/CU (was 3),
// 16 waves/CU, and 8 blocks/CU pack as 4+4 exact rounds. Warm-up is staged
// (fill s1 0-3, conv2 0-1, fill s1 4-5, conv2 2-3, conv3 0-1), then the loop
// rotates: h2p(st)+conv1(st+6) | conv2(st+4) | conv3(st+2)+scene-max.
__global__ __launch_bounds__(256, 4)
void enc_main(const float* __restrict__ obs,
              const float* __restrict__ Wse, const float* __restrict__ bse,
              const float* __restrict__ v1, const float* __restrict__ g1, const float* __restrict__ b1,
              const float* __restrict__ v2, const float* __restrict__ g2, const float* __restrict__ b2,
              const float* __restrict__ v3, const float* __restrict__ g3, const float* __restrict__ b3,
              const float* __restrict__ Whp, const float* __restrict__ bhp,
              float* __restrict__ out)
{
    __shared__ __align__(16) float pos[8][PEDS][2];                            //  1024 B
    __shared__ __align__(16) unsigned short s1h[4][PEDS][72], s1l[4][PEDS][72];// 18432 B
    __shared__ __align__(16) unsigned short s2h[4][PEDS][40], s2l[4][PEDS][40];// 10240 B
    __shared__ __align__(16) float sff[2][PEDS][68];                           //  8704 B (+prologue scratch)
    __shared__ __align__(16) float mxs[2][2][68];                              //  1088 B

    // prologue scratch overlaid on sff (dead before first sff write, conv3 col 0)
    float* wse_s = &sff[0][0][0];      // 128
    float* bse_s = wse_s + 128;        // 64
    float* sc_s  = wse_s + 192;        // 128
    float* a1c   = wse_s + 320;        // 192 (3 taps x 64 oc)
    float* b1c   = wse_s + 512;        // 192
    float* c1c   = wse_s + 704;        // 192   total 896 floats <= 2176
    const int tid  = threadIdx.x;
    const int wv   = tid >> 6;
    const int lane = tid & 63;
    const int n    = lane & 15;     // MFMA col = ped
    const int kg   = lane >> 4;

    // ---- stage Wse/bse + weight-norm scales ----
    if (tid < 128) wse_s[tid] = Wse[tid];
    else if (tid < 192) bse_s[tid-128] = bse[tid-128];
    if (tid < 64) {
        const float* v = v1 + tid*192; float s = 0.f;
        for (int j = 0; j < 192; j++) s += v[j]*v[j];
        sc_s[tid] = g1[tid] / sqrtf(s);
    } else if (tid < 96) {
        const float* v = v2 + (tid-64)*192; float s = 0.f;
        for (int j = 0; j < 192; j++) s += v[j]*v[j];
        sc_s[tid] = g2[tid-64] / sqrtf(s);
    } else if (tid < 128) {
        const float* v = v3 + (tid-96)*96; float s = 0.f;
        for (int j = 0; j < 96; j++) s += v[j]*v[j];
        sc_s[tid] = g3[tid-96] / sqrtf(s);
    }
    __syncthreads();

    // ---- stage position window + conv1 collapse coefficients ----
    {
        int tau = tid >> 5, p = (tid >> 1) & 15, c = tid & 1;
        pos[tau][p][c] = obs[(tau*BATCH + blockIdx.x*PEDS + p)*2 + c];
    }
    if (tid < 192) {
        int oc = tid & 63, tap = tid >> 6;
        const float* vr = v1 + oc*192 + tap;
        float dA = 0.f, dB = 0.f, dC = 0.f;
        #pragma unroll 8
        for (int ic = 0; ic < 64; ++ic) {
            float w = vr[ic*3];
            dA = fmaf(w, wse_s[ic*2],   dA);
            dB = fmaf(w, wse_s[ic*2+1], dB);
            dC = fmaf(w, bse_s[ic],     dC);
        }
        a1c[tap*64+oc] = dA; b1c[tap*64+oc] = dB; c1c[tap*64+oc] = dC;
    }
    __syncthreads();

    // ---- per-thread persistent registers ----
    // conv1 thread: ped c_p = tid>>4, 4 ocs at oc0 = (tid&15)*4
    const int c_p = tid >> 4, c_oc0 = (tid & 15) * 4;
    float cA[3][4], cB[3][4], K1[4];
    #pragma unroll
    for (int j = 0; j < 4; ++j) {
        int oc = c_oc0 + j; float s = sc_s[oc];
        float cs = 0.f;
        #pragma unroll
        for (int tap = 0; tap < 3; ++tap) {
            cA[tap][j] = s * a1c[tap*64+oc];
            cB[tap][j] = s * b1c[tap*64+oc];
            cs += c1c[tap*64+oc];
        }
        K1[j] = fmaf(s, cs, b1[oc]);
    }
    // MFMA A-fragments: waves 0,1 -> conv2 ; waves 2,3 -> conv3
    short8 wBh[6], wBl[6];
    float  bBr[4];
    if (wv < 2) {
        int oc = wv*16 + n; float s = sc_s[64 + oc];
        #pragma unroll
        for (int kb = 0; kb < 6; ++kb) {
            int tap = kb >> 1, ich = kb & 1;
            #pragma unroll
            for (int j = 0; j < 8; ++j) {
                int ic = ich*32 + kg*8 + j;
                float w = v2[(oc*64 + ic)*3 + tap] * s;
                unsigned short hb = f2bf(w);
                wBh[kb][j] = (short)hb;
                wBl[kb][j] = (short)f2bf(w - bf2f(hb));
            }
        }
        #pragma unroll
        for (int r = 0; r < 4; ++r) bBr[r] = b2[wv*16 + kg*4 + r];
    } else {
        int oc = (wv-2)*16 + n; float s = sc_s[96 + oc];
        #pragma unroll
        for (int kb = 0; kb < 3; ++kb) {
            #pragma unroll
            for (int j = 0; j < 8; ++j) {
                int ic = kg*8 + j;
                float w = v3[(oc*32 + ic)*3 + kb] * s;
                unsigned short hb = f2bf(w);
                wBh[kb][j] = (short)hb;
                wBl[kb][j] = (short)f2bf(w - bf2f(hb));
            }
        }
        #pragma unroll
        for (int r = 0; r < 4; ++r) bBr[r] = b3[(wv-2)*16 + kg*4 + r];
    }
    // h2p slice
    const int e_d = (tid >> 3) & 1, e_sl = tid & 7;
    float wreg[16];
    #pragma unroll
    for (int j = 0; j < 16; ++j) wreg[j] = Whp[e_d*128 + e_sl*16 + j];
    const float bhps = bhp[e_d];

    // ---- helpers ----
    // conv1 column writer: taps (pa, pb, (cx,cy)); exact fp32 affine, hi/lo pack.
    auto conv1_write = [&](int slot, float2 pa, float2 pb, float cx, float cy) {
        unsigned hw[2], lw[2];
        #pragma unroll
        for (int q = 0; q < 2; ++q) {
            float va, vb;
            {
                int j = q*2;
                va = K1[j];
                va = fmaf(cA[0][j], pa.x, va); va = fmaf(cB[0][j], pa.y, va);
                va = fmaf(cA[1][j], pb.x, va); va = fmaf(cB[1][j], pb.y, va);
                va = fmaf(cA[2][j], cx,   va); va = fmaf(cB[2][j], cy,   va);
                va = fmaxf(va, 0.f);
            }
            {
                int j = q*2+1;
                vb = K1[j];
                vb = fmaf(cA[0][j], pa.x, vb); vb = fmaf(cB[0][j], pa.y, vb);
                vb = fmaf(cA[1][j], pb.x, vb); vb = fmaf(cB[1][j], pb.y, vb);
                vb = fmaf(cA[2][j], cx,   vb); vb = fmaf(cB[2][j], cy,   vb);
                vb = fmaxf(vb, 0.f);
            }
            unsigned short ha = f2bf(va), hb = f2bf(vb);
            hw[q] = (unsigned)ha | ((unsigned)hb << 16);
            lw[q] = (unsigned)f2bf(va - bf2f(ha)) | ((unsigned)f2bf(vb - bf2f(hb)) << 16);
        }
        *(uint2*)&s1h[slot][c_p][c_oc0] = make_uint2(hw[0], hw[1]);
        *(uint2*)&s1l[slot][c_p][c_oc0] = make_uint2(lw[0], lw[1]);
    };
    auto conv1_obs_col = [&](int c) {   // columns whose 3 taps are all in pos ring
        float2 pa = *(const float2*)&pos[c  ][c_p][0];
        float2 pb = *(const float2*)&pos[c+1][c_p][0];
        float2 pc = *(const float2*)&pos[c+2][c_p][0];
        conv1_write(c & 3, pa, pb, pc.x, pc.y);
    };
    // conv2 column c: reads s1 cols c..c+2, writes s2 slot c&3 (waves 0,1)
    auto conv2_col = [&](int c) {
        f32x4 a1 = {0.f,0.f,0.f,0.f}, a2 = {0.f,0.f,0.f,0.f}, a3 = {0.f,0.f,0.f,0.f};
        #pragma unroll
        for (int kb = 0; kb < 6; ++kb) {
            int slot = (c + (kb >> 1)) & 3;
            int off  = (kb & 1)*32 + kg*8;
            short8 bh = *(const short8*)&s1h[slot][n][off];
            short8 bl = *(const short8*)&s1l[slot][n][off];
            a1 = __builtin_amdgcn_mfma_f32_16x16x32_bf16(wBh[kb], bh, a1, 0, 0, 0);
            a2 = __builtin_amdgcn_mfma_f32_16x16x32_bf16(wBh[kb], bl, a2, 0, 0, 0);
            a3 = __builtin_amdgcn_mfma_f32_16x16x32_bf16(wBl[kb], bh, a3, 0, 0, 0);
        }
        int slot2 = c & 3, oc0 = wv*16 + kg*4;
        float v0  = fmaxf(a1[0]+a2[0]+a3[0]+bBr[0], 0.f);
        float v1_ = fmaxf(a1[1]+a2[1]+a3[1]+bBr[1], 0.f);
        float v2_ = fmaxf(a1[2]+a2[2]+a3[2]+bBr[2], 0.f);
        float v3_ = fmaxf(a1[3]+a2[3]+a3[3]+bBr[3], 0.f);
        unsigned short h0=f2bf(v0), h1=f2bf(v1_), h2=f2bf(v2_), h3=f2bf(v3_);
        *(uint2*)&s2h[slot2][n][oc0] = make_uint2(
            (unsigned)h0 | ((unsigned)h1 << 16), (unsigned)h2 | ((unsigned)h3 << 16));
        *(uint2*)&s2l[slot2][n][oc0] = make_uint2(
            (unsigned)f2bf(v0-bf2f(h0)) | ((unsigned)f2bf(v1_-bf2f(h1)) << 16),
            (unsigned)f2bf(v2_-bf2f(h2)) | ((unsigned)f2bf(v3_-bf2f(h3)) << 16));
    };
    // conv3 column v: reads s2 cols v..v+2, writes sff/mxs[v&1] (waves 2,3)
    auto conv3_col = [&](int v) {
        f32x4 a1 = {0.f,0.f,0.f,0.f}, a2 = {0.f,0.f,0.f,0.f}, a3 = {0.f,0.f,0.f,0.f};
        #pragma unroll
        for (int kb = 0; kb < 3; ++kb) {
            int slot = (v + kb) & 3;
            short8 bh = *(const short8*)&s2h[slot][n][kg*8];
            short8 bl = *(const short8*)&s2l[slot][n][kg*8];
            a1 = __builtin_amdgcn_mfma_f32_16x16x32_bf16(wBh[kb], bh, a1, 0, 0, 0);
            a2 = __builtin_amdgcn_mfma_f32_16x16x32_bf16(wBh[kb], bl, a2, 0, 0, 0);
            a3 = __builtin_amdgcn_mfma_f32_16x16x32_bf16(wBl[kb], bh, a3, 0, 0, 0);
        }
        int sl01 = v & 1, oc0 = (wv-2)*16 + kg*4;
        float m0 = fmaxf(a1[0]+a2[0]+a3[0]+bBr[0], 0.f);
        float m1 = fmaxf(a1[1]+a2[1]+a3[1]+bBr[1], 0.f);
        float m2 = fmaxf(a1[2]+a2[2]+a3[2]+bBr[2], 0.f);
        float m3 = fmaxf(a1[3]+a2[3]+a3[3]+bBr[3], 0.f);
        *(float4*)&sff[sl01][n][oc0] = make_float4(m0, m1, m2, m3);
        #pragma unroll
        for (int msk = 1; msk <= 4; msk <<= 1) {
            m0 = fmaxf(m0, __shfl_xor(m0, msk));
            m1 = fmaxf(m1, __shfl_xor(m1, msk));
            m2 = fmaxf(m2, __shfl_xor(m2, msk));
            m3 = fmaxf(m3, __shfl_xor(m3, msk));
        }
        if ((n & 7) == 0)
            *(float4*)&mxs[sl01][n >> 3][oc0] = make_float4(m0, m1, m2, m3);
    };

    // ---- staged warm-up (4-slot s1 ring) ----
    conv1_obs_col(0); conv1_obs_col(1); conv1_obs_col(2); conv1_obs_col(3);
    __syncthreads();
    if (wv < 2) { conv2_col(0); conv2_col(1); }          // read s1 0..3
    __syncthreads();
    conv1_obs_col(4); conv1_obs_col(5);                  // overwrite slots 0,1
    __syncthreads();
    if (wv < 2) { conv2_col(2); conv2_col(3); }          // read s1 2..5
    __syncthreads();
    if (wv >= 2) { conv3_col(0); conv3_col(1); }         // read s2 0..3
    __syncthreads();

    // ---- main loop: h2p(st)+conv1(st+6) | conv2(st+4) | conv3(st+2) ----
    for (int st = 0; st < SEQLEN; ++st) {
        {
            int sE = st & 1, sO = (st + 1) & 1;
            float pv;
            if (e_sl < 4) {
                const float* A = &sff[sE][c_p][e_sl*8];
                const float* B = &sff[sO][c_p][e_sl*8];
                float4 a0 = *(const float4*)A, aq = *(const float4*)(A+4);
                float4 b0 = *(const float4*)B, bq = *(const float4*)(B+4);
                pv = wreg[0]*a0.x + wreg[1]*b0.x + wreg[2]*a0.y + wreg[3]*b0.y
                   + wreg[4]*a0.z + wreg[5]*b0.z + wreg[6]*a0.w + wreg[7]*b0.w
                   + wreg[8]*aq.x + wreg[9]*bq.x + wreg[10]*aq.y + wreg[11]*bq.y
                   + wreg[12]*aq.z + wreg[13]*bq.z + wreg[14]*aq.w + wreg[15]*bq.w;
            } else {
                int scn = c_p >> 3;
                const float* A = &mxs[sE][scn][(e_sl-4)*8];
                const float* B = &mxs[sO][scn][(e_sl-4)*8];
                float4 a0 = *(const float4*)A, aq = *(const float4*)(A+4);
                float4 b0 = *(const float4*)B, bq = *(const float4*)(B+4);
                pv = wreg[0]*a0.x + wreg[1]*b0.x + wreg[2]*a0.y + wreg[3]*b0.y
                   + wreg[4]*a0.z + wreg[5]*b0.z + wreg[6]*a0.w + wreg[7]*b0.w
                   + wreg[8]*aq.x + wreg[9]*bq.x + wreg[10]*aq.y + wreg[11]*bq.y
                   + wreg[12]*aq.z + wreg[13]*bq.z + wreg[14]*aq.w + wreg[15]*bq.w;
            }
            pv += __shfl_xor(pv, 1);
            pv += __shfl_xor(pv, 2);
            pv += __shfl_xor(pv, 4);
            float rm = pv + bhps;
            float ro = __shfl_xor(rm, 8);
            float r0 = e_d ? ro : rm;
            float r1 = e_d ? rm : ro;
            if (e_sl == 0)
                out[(st*BATCH + blockIdx.x*PEDS + c_p)*2 + e_d] = rm;
            if (st < SEQLEN-1) {
                // conv1 col st+6: taps = taus st+6, st+7, st+8(=new rel)
                float2 pa = *(const float2*)&pos[(st+6)&7][c_p][0];
                float2 pb = *(const float2*)&pos[(st+7)&7][c_p][0];
                conv1_write((st+6)&3, pa, pb, r0, r1);
                if (e_sl == 0)
                    pos[st & 7][c_p][e_d] = rm;   // tau st+8; distinct slot from reads
            }
        }
        if (st == SEQLEN-1) break;
        __syncthreads();
        if (wv < 2) conv2_col(st + 4);   // reads s1 st+4..st+6 (st+6 just written)
        __syncthreads();
        if (wv >= 2) conv3_col(st + 2);  // reads s2 st+2..st+4 (st+4 just written)
        __syncthreads();
    }
}

extern "C" void kernel_launch(void* const* d_in, const int* in_sizes, int n_in,
                              void* d_out, int out_size, void* d_ws, size_t ws_size,
                              hipStream_t stream)
{
    const float* obs = (const float*)d_in[0];
    // d_in[1] last_pos, d_in[2] last_pos_rel: dead state (never reaches output)
    const float* Wse = (const float*)d_in[3];
    const float* bse = (const float*)d_in[4];
    const float* v1  = (const float*)d_in[5];
    const float* g1  = (const float*)d_in[6];
    const float* b1  = (const float*)d_in[7];
    const float* v2  = (const float*)d_in[8];
    const float* g2  = (const float*)d_in[9];
    const float* b2  = (const float*)d_in[10];
    const float* v3  = (const float*)d_in[11];
    const float* g3  = (const float*)d_in[12];
    const float* b3  = (const float*)d_in[13];
    const float* Whp = (const float*)d_in[14];
    const float* bhp = (const float*)d_in[15];
    // d_in[16] seq_start_end: structurally seg = ped>>3 ; d_in[17] seq_len = 12

    enc_main<<<NBLK, 256, 0, stream>>>(obs, Wse, bse, v1, g1, b1, v2, g2, b2,
                                       v3, g3, b3, Whp, bhp, (float*)d_out);
}

// Round 2
// 236.668 us; speedup vs baseline: 1.1035x; 1.1035x over previous
//
#include <hip/hip_runtime.h>

#define BATCH 32768
#define SEQLEN 12
#define PEDS 16
#define NBLK (BATCH/PEDS)   // 2048

typedef short short8 __attribute__((ext_vector_type(8)));
typedef float f32x4 __attribute__((ext_vector_type(4)));

static __device__ __forceinline__ unsigned short f2bf(float x) {
    unsigned u = __float_as_uint(x);
    return (unsigned short)((u + 0x7FFFu + ((u >> 16) & 1u)) >> 16);  // RNE
}
static __device__ __forceinline__ float bf2f(unsigned short h) {
    return __uint_as_float(((unsigned)h) << 16);
}

// conv1 collapsed to affine form in raw positions (exact fp32).
// conv2/conv3 via MFMA with full 3-product bf16 hi/lo compensation.
//
// s1 ring = 4 slots (steady liveness: conv2 col c reads s1 c..c+2 while col
// c+3 is written) -> LDS 39936 B -> 4 blocks/CU.
// __launch_bounds__(256,3): round-1 evidence shows (256,4) caps the allocator
// at 64 arch-VGPRs -> spills -> 230 MB scratch traffic/dispatch (dur 134->187).
// With bound 3 the kernel compiles to ~84 VGPR, no scratch, and HW occupancy
// is LDS-limited at 4 blocks/CU. All phase bodies are macros: guaranteed
// textual inlining, no lambda call-frame risk.

// ---- phase-body macros (expand inside enc_main; reference its locals) ----
#define CONV1_WRITE(slot_, PAX, PAY, PBX, PBY, CX, CY) do {                   \
    unsigned hw_[2], lw_[2];                                                  \
    _Pragma("unroll")                                                         \
    for (int q_ = 0; q_ < 2; ++q_) {                                          \
        float va_, vb_;                                                       \
        { int j_ = q_*2;                                                      \
          va_ = K1[j_];                                                       \
          va_ = fmaf(cA[0][j_], PAX, va_); va_ = fmaf(cB[0][j_], PAY, va_);   \
          va_ = fmaf(cA[1][j_], PBX, va_); va_ = fmaf(cB[1][j_], PBY, va_);   \
          va_ = fmaf(cA[2][j_], CX,  va_); va_ = fmaf(cB[2][j_], CY,  va_);   \
          va_ = fmaxf(va_, 0.f); }                                            \
        { int j_ = q_*2+1;                                                    \
          vb_ = K1[j_];                                                       \
          vb_ = fmaf(cA[0][j_], PAX, vb_); vb_ = fmaf(cB[0][j_], PAY, vb_);   \
          vb_ = fmaf(cA[1][j_], PBX, vb_); vb_ = fmaf(cB[1][j_], PBY, vb_);   \
          vb_ = fmaf(cA[2][j_], CX,  vb_); vb_ = fmaf(cB[2][j_], CY,  vb_);   \
          vb_ = fmaxf(vb_, 0.f); }                                           \
        unsigned short ha_ = f2bf(va_), hb_ = f2bf(vb_);                      \
        hw_[q_] = (unsigned)ha_ | ((unsigned)hb_ << 16);                      \
        lw_[q_] = (unsigned)f2bf(va_ - bf2f(ha_))                             \
                | ((unsigned)f2bf(vb_ - bf2f(hb_)) << 16);                    \
    }                                                                         \
    *(uint2*)&s1h[slot_][c_p][c_oc0] = make_uint2(hw_[0], hw_[1]);            \
    *(uint2*)&s1l[slot_][c_p][c_oc0] = make_uint2(lw_[0], lw_[1]);            \
} while(0)

#define CONV1_OBS(c_) do {                                                    \
    float2 pa_ = *(const float2*)&pos[(c_)  ][c_p][0];                        \
    float2 pb_ = *(const float2*)&pos[(c_)+1][c_p][0];                        \
    float2 pc_ = *(const float2*)&pos[(c_)+2][c_p][0];                        \
    CONV1_WRITE((c_) & 3, pa_.x, pa_.y, pb_.x, pb_.y, pc_.x, pc_.y);          \
} while(0)

// conv2 column c: reads s1 cols c..c+2, writes s2 slot c&3 (waves 0,1)
#define CONV2_COL(c_) do {                                                    \
    f32x4 a1_ = {0.f,0.f,0.f,0.f}, a2_ = {0.f,0.f,0.f,0.f},                   \
          a3_ = {0.f,0.f,0.f,0.f};                                            \
    _Pragma("unroll")                                                         \
    for (int kb_ = 0; kb_ < 6; ++kb_) {                                       \
        int slot_ = ((c_) + (kb_ >> 1)) & 3;                                  \
        int off_  = (kb_ & 1)*32 + kg*8;                                      \
        short8 bh_ = *(const short8*)&s1h[slot_][n][off_];                    \
        short8 bl_ = *(const short8*)&s1l[slot_][n][off_];                    \
        a1_ = __builtin_amdgcn_mfma_f32_16x16x32_bf16(wBh[kb_], bh_, a1_, 0, 0, 0); \
        a2_ = __builtin_amdgcn_mfma_f32_16x16x32_bf16(wBh[kb_], bl_, a2_, 0, 0, 0); \
        a3_ = __builtin_amdgcn_mfma_f32_16x16x32_bf16(wBl[kb_], bh_, a3_, 0, 0, 0); \
    }                                                                         \
    int slot2_ = (c_) & 3, oc0_ = wv*16 + kg*4;                               \
    float w0_ = fmaxf(a1_[0]+a2_[0]+a3_[0]+bBr[0], 0.f);                      \
    float w1_ = fmaxf(a1_[1]+a2_[1]+a3_[1]+bBr[1], 0.f);                      \
    float w2_ = fmaxf(a1_[2]+a2_[2]+a3_[2]+bBr[2], 0.f);                      \
    float w3_ = fmaxf(a1_[3]+a2_[3]+a3_[3]+bBr[3], 0.f);                      \
    unsigned short h0_=f2bf(w0_), h1_=f2bf(w1_), h2_=f2bf(w2_), h3_=f2bf(w3_);\
    *(uint2*)&s2h[slot2_][n][oc0_] = make_uint2(                              \
        (unsigned)h0_ | ((unsigned)h1_ << 16),                                \
        (unsigned)h2_ | ((unsigned)h3_ << 16));                               \
    *(uint2*)&s2l[slot2_][n][oc0_] = make_uint2(                              \
        (unsigned)f2bf(w0_-bf2f(h0_)) | ((unsigned)f2bf(w1_-bf2f(h1_)) << 16),\
        (unsigned)f2bf(w2_-bf2f(h2_)) | ((unsigned)f2bf(w3_-bf2f(h3_)) << 16));\
} while(0)

// conv3 column v: reads s2 cols v..v+2, writes sff/mxs[v&1] (waves 2,3)
#define CONV3_COL(v_) do {                                                    \
    f32x4 a1_ = {0.f,0.f,0.f,0.f}, a2_ = {0.f,0.f,0.f,0.f},                   \
          a3_ = {0.f,0.f,0.f,0.f};                                            \
    _Pragma("unroll")                                                         \
    for (int kb_ = 0; kb_ < 3; ++kb_) {                                       \
        int slot_ = ((v_) + kb_) & 3;                                         \
        short8 bh_ = *(const short8*)&s2h[slot_][n][kg*8];                    \
        short8 bl_ = *(const short8*)&s2l[slot_][n][kg*8];                    \
        a1_ = __builtin_amdgcn_mfma_f32_16x16x32_bf16(wBh[kb_], bh_, a1_, 0, 0, 0); \
        a2_ = __builtin_amdgcn_mfma_f32_16x16x32_bf16(wBh[kb_], bl_, a2_, 0, 0, 0); \
        a3_ = __builtin_amdgcn_mfma_f32_16x16x32_bf16(wBl[kb_], bh_, a3_, 0, 0, 0); \
    }                                                                         \
    int sl01_ = (v_) & 1, oc0_ = (wv-2)*16 + kg*4;                            \
    float m0_ = fmaxf(a1_[0]+a2_[0]+a3_[0]+bBr[0], 0.f);                      \
    float m1_ = fmaxf(a1_[1]+a2_[1]+a3_[1]+bBr[1], 0.f);                      \
    float m2_ = fmaxf(a1_[2]+a2_[2]+a3_[2]+bBr[2], 0.f);                      \
    float m3_ = fmaxf(a1_[3]+a2_[3]+a3_[3]+bBr[3], 0.f);                      \
    *(float4*)&sff[sl01_][n][oc0_] = make_float4(m0_, m1_, m2_, m3_);         \
    _Pragma("unroll")                                                         \
    for (int msk_ = 1; msk_ <= 4; msk_ <<= 1) {                               \
        m0_ = fmaxf(m0_, __shfl_xor(m0_, msk_));                              \
        m1_ = fmaxf(m1_, __shfl_xor(m1_, msk_));                              \
        m2_ = fmaxf(m2_, __shfl_xor(m2_, msk_));                              \
        m3_ = fmaxf(m3_, __shfl_xor(m3_, msk_));                              \
    }                                                                         \
    if ((n & 7) == 0)                                                         \
        *(float4*)&mxs[sl01_][n >> 3][oc0_] = make_float4(m0_, m1_, m2_, m3_);\
} while(0)

__global__ __launch_bounds__(256, 3)
void enc_main(const float* __restrict__ obs,
              const float* __restrict__ Wse, const float* __restrict__ bse,
              const float* __restrict__ v1, const float* __restrict__ g1, const float* __restrict__ b1,
              const float* __restrict__ v2, const float* __restrict__ g2, const float* __restrict__ b2,
              const float* __restrict__ v3, const float* __restrict__ g3, const float* __restrict__ b3,
              const float* __restrict__ Whp, const float* __restrict__ bhp,
              float* __restrict__ out)
{
    __shared__ __align__(16) float pos[8][PEDS][2];                            //  1024 B
    __shared__ __align__(16) unsigned short s1h[4][PEDS][72], s1l[4][PEDS][72];// 18432 B
    __shared__ __align__(16) unsigned short s2h[4][PEDS][40], s2l[4][PEDS][40];// 10240 B
    __shared__ __align__(16) float sff[2][PEDS][68];                           //  8704 B (+prologue scratch)
    __shared__ __align__(16) float mxs[2][2][68];                              //  1088 B
                                                                               // total 39488 -> 39936 granule

    // prologue scratch overlaid on sff (dead before first sff write, conv3 col 0)
    float* wse_s = &sff[0][0][0];      // 128
    float* bse_s = wse_s + 128;        // 64
    float* sc_s  = wse_s + 192;        // 128
    float* a1c   = wse_s + 320;        // 192 (3 taps x 64 oc)
    float* b1c   = wse_s + 512;        // 192
    float* c1c   = wse_s + 704;        // 192   total 896 floats <= 2176
    const int tid  = threadIdx.x;
    const int wv   = tid >> 6;
    const int lane = tid & 63;
    const int n    = lane & 15;     // MFMA col = ped
    const int kg   = lane >> 4;

    // ---- stage Wse/bse + weight-norm scales ----
    if (tid < 128) wse_s[tid] = Wse[tid];
    else if (tid < 192) bse_s[tid-128] = bse[tid-128];
    if (tid < 64) {
        const float* v = v1 + tid*192; float s = 0.f;
        for (int j = 0; j < 192; j++) s += v[j]*v[j];
        sc_s[tid] = g1[tid] / sqrtf(s);
    } else if (tid < 96) {
        const float* v = v2 + (tid-64)*192; float s = 0.f;
        for (int j = 0; j < 192; j++) s += v[j]*v[j];
        sc_s[tid] = g2[tid-64] / sqrtf(s);
    } else if (tid < 128) {
        const float* v = v3 + (tid-96)*96; float s = 0.f;
        for (int j = 0; j < 96; j++) s += v[j]*v[j];
        sc_s[tid] = g3[tid-96] / sqrtf(s);
    }
    __syncthreads();

    // ---- stage position window + conv1 collapse coefficients ----
    {
        int tau = tid >> 5, p = (tid >> 1) & 15, c = tid & 1;
        pos[tau][p][c] = obs[(tau*BATCH + blockIdx.x*PEDS + p)*2 + c];
    }
    if (tid < 192) {
        int oc = tid & 63, tap = tid >> 6;
        const float* vr = v1 + oc*192 + tap;
        float dA = 0.f, dB = 0.f, dC = 0.f;
        #pragma unroll 8
        for (int ic = 0; ic < 64; ++ic) {
            float w = vr[ic*3];
            dA = fmaf(w, wse_s[ic*2],   dA);
            dB = fmaf(w, wse_s[ic*2+1], dB);
            dC = fmaf(w, bse_s[ic],     dC);
        }
        a1c[tap*64+oc] = dA; b1c[tap*64+oc] = dB; c1c[tap*64+oc] = dC;
    }
    __syncthreads();

    // ---- per-thread persistent registers ----
    // conv1 thread: ped c_p = tid>>4, 4 ocs at oc0 = (tid&15)*4
    const int c_p = tid >> 4, c_oc0 = (tid & 15) * 4;
    float cA[3][4], cB[3][4], K1[4];
    #pragma unroll
    for (int j = 0; j < 4; ++j) {
        int oc = c_oc0 + j; float s = sc_s[oc];
        float cs = 0.f;
        #pragma unroll
        for (int tap = 0; tap < 3; ++tap) {
            cA[tap][j] = s * a1c[tap*64+oc];
            cB[tap][j] = s * b1c[tap*64+oc];
            cs += c1c[tap*64+oc];
        }
        K1[j] = fmaf(s, cs, b1[oc]);
    }
    // MFMA A-fragments: waves 0,1 -> conv2 ; waves 2,3 -> conv3
    short8 wBh[6], wBl[6];
    float  bBr[4];
    if (wv < 2) {
        int oc = wv*16 + n; float s = sc_s[64 + oc];
        #pragma unroll
        for (int kb = 0; kb < 6; ++kb) {
            int tap = kb >> 1, ich = kb & 1;
            #pragma unroll
            for (int j = 0; j < 8; ++j) {
                int ic = ich*32 + kg*8 + j;
                float w = v2[(oc*64 + ic)*3 + tap] * s;
                unsigned short hb = f2bf(w);
                wBh[kb][j] = (short)hb;
                wBl[kb][j] = (short)f2bf(w - bf2f(hb));
            }
        }
        #pragma unroll
        for (int r = 0; r < 4; ++r) bBr[r] = b2[wv*16 + kg*4 + r];
    } else {
        int oc = (wv-2)*16 + n; float s = sc_s[96 + oc];
        #pragma unroll
        for (int kb = 0; kb < 3; ++kb) {
            #pragma unroll
            for (int j = 0; j < 8; ++j) {
                int ic = kg*8 + j;
                float w = v3[(oc*32 + ic)*3 + kb] * s;
                unsigned short hb = f2bf(w);
                wBh[kb][j] = (short)hb;
                wBl[kb][j] = (short)f2bf(w - bf2f(hb));
            }
        }
        #pragma unroll
        for (int r = 0; r < 4; ++r) bBr[r] = b3[(wv-2)*16 + kg*4 + r];
    }
    // h2p slice
    const int e_d = (tid >> 3) & 1, e_sl = tid & 7;
    float wreg[16];
    #pragma unroll
    for (int j = 0; j < 16; ++j) wreg[j] = Whp[e_d*128 + e_sl*16 + j];
    const float bhps = bhp[e_d];

    // ---- staged warm-up (4-slot s1 ring) ----
    CONV1_OBS(0); CONV1_OBS(1); CONV1_OBS(2); CONV1_OBS(3);
    __syncthreads();
    if (wv < 2) { CONV2_COL(0); CONV2_COL(1); }          // read s1 0..3
    __syncthreads();
    CONV1_OBS(4); CONV1_OBS(5);                          // overwrite slots 0,1
    __syncthreads();
    if (wv < 2) { CONV2_COL(2); CONV2_COL(3); }          // read s1 2..5
    __syncthreads();
    if (wv >= 2) { CONV3_COL(0); CONV3_COL(1); }         // read s2 0..3
    __syncthreads();

    // ---- main loop: h2p(st)+conv1(st+6) | conv2(st+4) | conv3(st+2) ----
    for (int st = 0; st < SEQLEN; ++st) {
        {
            int sE = st & 1, sO = (st + 1) & 1;
            float pv;
            if (e_sl < 4) {
                const float* A = &sff[sE][c_p][e_sl*8];
                const float* B = &sff[sO][c_p][e_sl*8];
                float4 a0 = *(const float4*)A, aq = *(const float4*)(A+4);
                float4 b0 = *(const float4*)B, bq = *(const float4*)(B+4);
                pv = wreg[0]*a0.x + wreg[1]*b0.x + wreg[2]*a0.y + wreg[3]*b0.y
                   + wreg[4]*a0.z + wreg[5]*b0.z + wreg[6]*a0.w + wreg[7]*b0.w
                   + wreg[8]*aq.x + wreg[9]*bq.x + wreg[10]*aq.y + wreg[11]*bq.y
                   + wreg[12]*aq.z + wreg[13]*bq.z + wreg[14]*aq.w + wreg[15]*bq.w;
            } else {
                int scn = c_p >> 3;
                const float* A = &mxs[sE][scn][(e_sl-4)*8];
                const float* B = &mxs[sO][scn][(e_sl-4)*8];
                float4 a0 = *(const float4*)A, aq = *(const float4*)(A+4);
                float4 b0 = *(const float4*)B, bq = *(const float4*)(B+4);
                pv = wreg[0]*a0.x + wreg[1]*b0.x + wreg[2]*a0.y + wreg[3]*b0.y
                   + wreg[4]*a0.z + wreg[5]*b0.z + wreg[6]*a0.w + wreg[7]*b0.w
                   + wreg[8]*aq.x + wreg[9]*bq.x + wreg[10]*aq.y + wreg[11]*bq.y
                   + wreg[12]*aq.z + wreg[13]*bq.z + wreg[14]*aq.w + wreg[15]*bq.w;
            }
            pv += __shfl_xor(pv, 1);
            pv += __shfl_xor(pv, 2);
            pv += __shfl_xor(pv, 4);
            float rm = pv + bhps;
            float ro = __shfl_xor(rm, 8);
            float r0 = e_d ? ro : rm;
            float r1 = e_d ? rm : ro;
            if (e_sl == 0)
                out[(st*BATCH + blockIdx.x*PEDS + c_p)*2 + e_d] = rm;
            if (st < SEQLEN-1) {
                // conv1 col st+6: taps = taus st+6, st+7, st+8(=new rel)
                float2 pa = *(const float2*)&pos[(st+6)&7][c_p][0];
                float2 pb = *(const float2*)&pos[(st+7)&7][c_p][0];
                CONV1_WRITE((st+6)&3, pa.x, pa.y, pb.x, pb.y, r0, r1);
                if (e_sl == 0)
                    pos[st & 7][c_p][e_d] = rm;   // tau st+8; distinct slot from reads
            }
        }
        if (st == SEQLEN-1) break;
        __syncthreads();
        if (wv < 2) CONV2_COL(st + 4);   // reads s1 st+4..st+6 (st+6 just written)
        __syncthreads();
        if (wv >= 2) CONV3_COL(st + 2);  // reads s2 st+2..st+4 (st+4 just written)
        __syncthreads();
    }
}

extern "C" void kernel_launch(void* const* d_in, const int* in_sizes, int n_in,
                              void* d_out, int out_size, void* d_ws, size_t ws_size,
                              hipStream_t stream)
{
    const float* obs = (const float*)d_in[0];
    // d_in[1] last_pos, d_in[2] last_pos_rel: dead state (never reaches output)
    const float* Wse = (const float*)d_in[3];
    const float* bse = (const float*)d_in[4];
    const float* v1  = (const float*)d_in[5];
    const float* g1  = (const float*)d_in[6];
    const float* b1  = (const float*)d_in[7];
    const float* v2  = (const float*)d_in[8];
    const float* g2  = (const float*)d_in[9];
    const float* b2  = (const float*)d_in[10];
    const float* v3  = (const float*)d_in[11];
    const float* g3  = (const float*)d_in[12];
    const float* b3  = (const float*)d_in[13];
    const float* Whp = (const float*)d_in[14];
    const float* bhp = (const float*)d_in[15];
    // d_in[16] seq_start_end: structurally seg = ped>>3 ; d_in[17] seq_len = 12

    enc_main<<<NBLK, 256, 0, stream>>>(obs, Wse, bse, v1, g1, b1, v2, g2, b2,
                                       v3, g3, b3, Whp, bhp, (float*)d_out);
}

// Round 3
// 209.389 us; speedup vs baseline: 1.2472x; 1.1303x over previous
//
#include <hip/hip_runtime.h>

#define BATCH 32768
#define SEQLEN 12
#define PEDS 16
#define NBLK (BATCH/PEDS)   // 2048

typedef short short8 __attribute__((ext_vector_type(8)));
typedef float f32x4 __attribute__((ext_vector_type(4)));

static __device__ __forceinline__ unsigned short f2bf(float x) {
    unsigned u = __float_as_uint(x);
    return (unsigned short)((u + 0x7FFFu + ((u >> 16) & 1u)) >> 16);  // RNE
}
static __device__ __forceinline__ float bf2f(unsigned short h) {
    return __uint_as_float(((unsigned)h) << 16);
}

// conv1 collapsed to affine form in raw positions (exact fp32).
// conv2/conv3 via MFMA with full 3-product bf16 hi/lo compensation.
//
// s1 ring = 4 slots -> LDS 39936 B -> 4 blocks/CU (vs 3 at the 6-slot 48 KB).
// Round-2 lesson: a straight-line warm-up with h2p weights live across it
// spilled ~128 B/thread to scratch (WRITE_SIZE 3->70 MB, dur 134->171 us).
// Fixes here: (a) warm-up phases are ROLLED loops (#pragma unroll 1),
// (b) wreg/bhps are loaded AFTER the warm-up so nothing h2p-related is live
// across it, (c) main loop is #pragma unroll 1. launch_bounds(256,3): the
// (256,4) bound caps the allocator at 64 VGPR and force-spills (round 1).

// ---- phase-body macros (expand inside enc_main; reference its locals) ----
#define CONV1_WRITE(slot_, PAX, PAY, PBX, PBY, CX, CY) do {                   \
    unsigned hw_[2], lw_[2];                                                  \
    _Pragma("unroll")                                                         \
    for (int q_ = 0; q_ < 2; ++q_) {                                          \
        float va_, vb_;                                                       \
        { int j_ = q_*2;                                                      \
          va_ = K1[j_];                                                       \
          va_ = fmaf(cA[0][j_], PAX, va_); va_ = fmaf(cB[0][j_], PAY, va_);   \
          va_ = fmaf(cA[1][j_], PBX, va_); va_ = fmaf(cB[1][j_], PBY, va_);   \
          va_ = fmaf(cA[2][j_], CX,  va_); va_ = fmaf(cB[2][j_], CY,  va_);   \
          va_ = fmaxf(va_, 0.f); }                                            \
        { int j_ = q_*2+1;                                                    \
          vb_ = K1[j_];                                                       \
          vb_ = fmaf(cA[0][j_], PAX, vb_); vb_ = fmaf(cB[0][j_], PAY, vb_);   \
          vb_ = fmaf(cA[1][j_], PBX, vb_); vb_ = fmaf(cB[1][j_], PBY, vb_);   \
          vb_ = fmaf(cA[2][j_], CX,  vb_); vb_ = fmaf(cB[2][j_], CY,  vb_);   \
          vb_ = fmaxf(vb_, 0.f); }                                           \
        unsigned short ha_ = f2bf(va_), hb_ = f2bf(vb_);                      \
        hw_[q_] = (unsigned)ha_ | ((unsigned)hb_ << 16);                      \
        lw_[q_] = (unsigned)f2bf(va_ - bf2f(ha_))                             \
                | ((unsigned)f2bf(vb_ - bf2f(hb_)) << 16);                    \
    }                                                                         \
    *(uint2*)&s1h[slot_][c_p][c_oc0] = make_uint2(hw_[0], hw_[1]);            \
    *(uint2*)&s1l[slot_][c_p][c_oc0] = make_uint2(lw_[0], lw_[1]);            \
} while(0)

#define CONV1_OBS(c_) do {                                                    \
    float2 pa_ = *(const float2*)&pos[(c_)  ][c_p][0];                        \
    float2 pb_ = *(const float2*)&pos[(c_)+1][c_p][0];                        \
    float2 pc_ = *(const float2*)&pos[(c_)+2][c_p][0];                        \
    CONV1_WRITE((c_) & 3, pa_.x, pa_.y, pb_.x, pb_.y, pc_.x, pc_.y);          \
} while(0)

// conv2 column c: reads s1 cols c..c+2, writes s2 slot c&3 (waves 0,1)
#define CONV2_COL(c_) do {                                                    \
    f32x4 a1_ = {0.f,0.f,0.f,0.f}, a2_ = {0.f,0.f,0.f,0.f},                   \
          a3_ = {0.f,0.f,0.f,0.f};                                            \
    _Pragma("unroll")                                                         \
    for (int kb_ = 0; kb_ < 6; ++kb_) {                                       \
        int slot_ = ((c_) + (kb_ >> 1)) & 3;                                  \
        int off_  = (kb_ & 1)*32 + kg*8;                                      \
        short8 bh_ = *(const short8*)&s1h[slot_][n][off_];                    \
        short8 bl_ = *(const short8*)&s1l[slot_][n][off_];                    \
        a1_ = __builtin_amdgcn_mfma_f32_16x16x32_bf16(wBh[kb_], bh_, a1_, 0, 0, 0); \
        a2_ = __builtin_amdgcn_mfma_f32_16x16x32_bf16(wBh[kb_], bl_, a2_, 0, 0, 0); \
        a3_ = __builtin_amdgcn_mfma_f32_16x16x32_bf16(wBl[kb_], bh_, a3_, 0, 0, 0); \
    }                                                                         \
    int slot2_ = (c_) & 3, oc0_ = wv*16 + kg*4;                               \
    float w0_ = fmaxf(a1_[0]+a2_[0]+a3_[0]+bBr[0], 0.f);                      \
    float w1_ = fmaxf(a1_[1]+a2_[1]+a3_[1]+bBr[1], 0.f);                      \
    float w2_ = fmaxf(a1_[2]+a2_[2]+a3_[2]+bBr[2], 0.f);                      \
    float w3_ = fmaxf(a1_[3]+a2_[3]+a3_[3]+bBr[3], 0.f);                      \
    unsigned short h0_=f2bf(w0_), h1_=f2bf(w1_), h2_=f2bf(w2_), h3_=f2bf(w3_);\
    *(uint2*)&s2h[slot2_][n][oc0_] = make_uint2(                              \
        (unsigned)h0_ | ((unsigned)h1_ << 16),                                \
        (unsigned)h2_ | ((unsigned)h3_ << 16));                               \
    *(uint2*)&s2l[slot2_][n][oc0_] = make_uint2(                              \
        (unsigned)f2bf(w0_-bf2f(h0_)) | ((unsigned)f2bf(w1_-bf2f(h1_)) << 16),\
        (unsigned)f2bf(w2_-bf2f(h2_)) | ((unsigned)f2bf(w3_-bf2f(h3_)) << 16));\
} while(0)

// conv3 column v: reads s2 cols v..v+2, writes sff/mxs[v&1] (waves 2,3)
#define CONV3_COL(v_) do {                                                    \
    f32x4 a1_ = {0.f,0.f,0.f,0.f}, a2_ = {0.f,0.f,0.f,0.f},                   \
          a3_ = {0.f,0.f,0.f,0.f};                                            \
    _Pragma("unroll")                                                         \
    for (int kb_ = 0; kb_ < 3; ++kb_) {                                       \
        int slot_ = ((v_) + kb_) & 3;                                         \
        short8 bh_ = *(const short8*)&s2h[slot_][n][kg*8];                    \
        short8 bl_ = *(const short8*)&s2l[slot_][n][kg*8];                    \
        a1_ = __builtin_amdgcn_mfma_f32_16x16x32_bf16(wBh[kb_], bh_, a1_, 0, 0, 0); \
        a2_ = __builtin_amdgcn_mfma_f32_16x16x32_bf16(wBh[kb_], bl_, a2_, 0, 0, 0); \
        a3_ = __builtin_amdgcn_mfma_f32_16x16x32_bf16(wBl[kb_], bh_, a3_, 0, 0, 0); \
    }                                                                         \
    int sl01_ = (v_) & 1, oc0_ = (wv-2)*16 + kg*4;                            \
    float m0_ = fmaxf(a1_[0]+a2_[0]+a3_[0]+bBr[0], 0.f);                      \
    float m1_ = fmaxf(a1_[1]+a2_[1]+a3_[1]+bBr[1], 0.f);                      \
    float m2_ = fmaxf(a1_[2]+a2_[2]+a3_[2]+bBr[2], 0.f);                      \
    float m3_ = fmaxf(a1_[3]+a2_[3]+a3_[3]+bBr[3], 0.f);                      \
    *(float4*)&sff[sl01_][n][oc0_] = make_float4(m0_, m1_, m2_, m3_);         \
    _Pragma("unroll")                                                         \
    for (int msk_ = 1; msk_ <= 4; msk_ <<= 1) {                               \
        m0_ = fmaxf(m0_, __shfl_xor(m0_, msk_));                              \
        m1_ = fmaxf(m1_, __shfl_xor(m1_, msk_));                              \
        m2_ = fmaxf(m2_, __shfl_xor(m2_, msk_));                              \
        m3_ = fmaxf(m3_, __shfl_xor(m3_, msk_));                              \
    }                                                                         \
    if ((n & 7) == 0)                                                         \
        *(float4*)&mxs[sl01_][n >> 3][oc0_] = make_float4(m0_, m1_, m2_, m3_);\
} while(0)

__global__ __launch_bounds__(256, 3)
void enc_main(const float* __restrict__ obs,
              const float* __restrict__ Wse, const float* __restrict__ bse,
              const float* __restrict__ v1, const float* __restrict__ g1, const float* __restrict__ b1,
              const float* __restrict__ v2, const float* __restrict__ g2, const float* __restrict__ b2,
              const float* __restrict__ v3, const float* __restrict__ g3, const float* __restrict__ b3,
              const float* __restrict__ Whp, const float* __restrict__ bhp,
              float* __restrict__ out)
{
    __shared__ __align__(16) float pos[8][PEDS][2];                            //  1024 B
    __shared__ __align__(16) unsigned short s1h[4][PEDS][72], s1l[4][PEDS][72];// 18432 B
    __shared__ __align__(16) unsigned short s2h[4][PEDS][40], s2l[4][PEDS][40];// 10240 B
    __shared__ __align__(16) float sff[2][PEDS][68];                           //  8704 B (+prologue scratch)
    __shared__ __align__(16) float mxs[2][2][68];                              //  1088 B
                                                                               // total 39488 -> 39936 granule

    // prologue scratch overlaid on sff (dead before first sff write, conv3 col 0)
    float* wse_s = &sff[0][0][0];      // 128
    float* bse_s = wse_s + 128;        // 64
    float* sc_s  = wse_s + 192;        // 128
    float* a1c   = wse_s + 320;        // 192 (3 taps x 64 oc)
    float* b1c   = wse_s + 512;        // 192
    float* c1c   = wse_s + 704;        // 192   total 896 floats <= 2176
    const int tid  = threadIdx.x;
    const int wv   = tid >> 6;
    const int lane = tid & 63;
    const int n    = lane & 15;     // MFMA col = ped
    const int kg   = lane >> 4;

    // ---- stage Wse/bse + weight-norm scales ----
    if (tid < 128) wse_s[tid] = Wse[tid];
    else if (tid < 192) bse_s[tid-128] = bse[tid-128];
    if (tid < 64) {
        const float* v = v1 + tid*192; float s = 0.f;
        for (int j = 0; j < 192; j++) s += v[j]*v[j];
        sc_s[tid] = g1[tid] / sqrtf(s);
    } else if (tid < 96) {
        const float* v = v2 + (tid-64)*192; float s = 0.f;
        for (int j = 0; j < 192; j++) s += v[j]*v[j];
        sc_s[tid] = g2[tid-64] / sqrtf(s);
    } else if (tid < 128) {
        const float* v = v3 + (tid-96)*96; float s = 0.f;
        for (int j = 0; j < 96; j++) s += v[j]*v[j];
        sc_s[tid] = g3[tid-96] / sqrtf(s);
    }
    __syncthreads();

    // ---- stage position window + conv1 collapse coefficients ----
    {
        int tau = tid >> 5, p = (tid >> 1) & 15, c = tid & 1;
        pos[tau][p][c] = obs[(tau*BATCH + blockIdx.x*PEDS + p)*2 + c];
    }
    if (tid < 192) {
        int oc = tid & 63, tap = tid >> 6;
        const float* vr = v1 + oc*192 + tap;
        float dA = 0.f, dB = 0.f, dC = 0.f;
        #pragma unroll 8
        for (int ic = 0; ic < 64; ++ic) {
            float w = vr[ic*3];
            dA = fmaf(w, wse_s[ic*2],   dA);
            dB = fmaf(w, wse_s[ic*2+1], dB);
            dC = fmaf(w, bse_s[ic],     dC);
        }
        a1c[tap*64+oc] = dA; b1c[tap*64+oc] = dB; c1c[tap*64+oc] = dC;
    }
    __syncthreads();

    // ---- per-thread persistent registers ----
    // conv1 thread: ped c_p = tid>>4, 4 ocs at oc0 = (tid&15)*4
    const int c_p = tid >> 4, c_oc0 = (tid & 15) * 4;
    float cA[3][4], cB[3][4], K1[4];
    #pragma unroll
    for (int j = 0; j < 4; ++j) {
        int oc = c_oc0 + j; float s = sc_s[oc];
        float cs = 0.f;
        #pragma unroll
        for (int tap = 0; tap < 3; ++tap) {
            cA[tap][j] = s * a1c[tap*64+oc];
            cB[tap][j] = s * b1c[tap*64+oc];
            cs += c1c[tap*64+oc];
        }
        K1[j] = fmaf(s, cs, b1[oc]);
    }
    // MFMA A-fragments: waves 0,1 -> conv2 ; waves 2,3 -> conv3
    short8 wBh[6], wBl[6];
    float  bBr[4];
    if (wv < 2) {
        int oc = wv*16 + n; float s = sc_s[64 + oc];
        #pragma unroll
        for (int kb = 0; kb < 6; ++kb) {
            int tap = kb >> 1, ich = kb & 1;
            #pragma unroll
            for (int j = 0; j < 8; ++j) {
                int ic = ich*32 + kg*8 + j;
                float w = v2[(oc*64 + ic)*3 + tap] * s;
                unsigned short hb = f2bf(w);
                wBh[kb][j] = (short)hb;
                wBl[kb][j] = (short)f2bf(w - bf2f(hb));
            }
        }
        #pragma unroll
        for (int r = 0; r < 4; ++r) bBr[r] = b2[wv*16 + kg*4 + r];
    } else {
        int oc = (wv-2)*16 + n; float s = sc_s[96 + oc];
        #pragma unroll
        for (int kb = 0; kb < 3; ++kb) {
            #pragma unroll
            for (int j = 0; j < 8; ++j) {
                int ic = kg*8 + j;
                float w = v3[(oc*32 + ic)*3 + kb] * s;
                unsigned short hb = f2bf(w);
                wBh[kb][j] = (short)hb;
                wBl[kb][j] = (short)f2bf(w - bf2f(hb));
            }
        }
        #pragma unroll
        for (int r = 0; r < 4; ++r) bBr[r] = b3[(wv-2)*16 + kg*4 + r];
    }

    // ---- staged warm-up (4-slot s1 ring) -- rolled loops, short live ranges ----
    #pragma unroll 1
    for (int c = 0; c < 4; ++c) CONV1_OBS(c);            // slots 0..3
    __syncthreads();
    if (wv < 2) {
        #pragma unroll 1
        for (int c = 0; c < 2; ++c) CONV2_COL(c);        // read s1 0..3
    }
    __syncthreads();
    #pragma unroll 1
    for (int c = 4; c < 6; ++c) CONV1_OBS(c);            // overwrite slots 0,1
    __syncthreads();
    if (wv < 2) {
        #pragma unroll 1
        for (int c = 2; c < 4; ++c) CONV2_COL(c);        // read s1 2..5
    }
    __syncthreads();
    if (wv >= 2) {
        #pragma unroll 1
        for (int v = 0; v < 2; ++v) CONV3_COL(v);        // read s2 0..3
    }

    // ---- h2p slice: loaded AFTER warm-up so it is not live across it ----
    const int e_d = (tid >> 3) & 1, e_sl = tid & 7;
    float wreg[16];
    #pragma unroll
    for (int j = 0; j < 16; ++j) wreg[j] = Whp[e_d*128 + e_sl*16 + j];
    const float bhps = bhp[e_d];
    __syncthreads();

    // ---- main loop: h2p(st)+conv1(st+6) | conv2(st+4) | conv3(st+2) ----
    #pragma unroll 1
    for (int st = 0; st < SEQLEN; ++st) {
        {
            int sE = st & 1, sO = (st + 1) & 1;
            float pv;
            if (e_sl < 4) {
                const float* A = &sff[sE][c_p][e_sl*8];
                const float* B = &sff[sO][c_p][e_sl*8];
                float4 a0 = *(const float4*)A, aq = *(const float4*)(A+4);
                float4 b0 = *(const float4*)B, bq = *(const float4*)(B+4);
                pv = wreg[0]*a0.x + wreg[1]*b0.x + wreg[2]*a0.y + wreg[3]*b0.y
                   + wreg[4]*a0.z + wreg[5]*b0.z + wreg[6]*a0.w + wreg[7]*b0.w
                   + wreg[8]*aq.x + wreg[9]*bq.x + wreg[10]*aq.y + wreg[11]*bq.y
                   + wreg[12]*aq.z + wreg[13]*bq.z + wreg[14]*aq.w + wreg[15]*bq.w;
            } else {
                int scn = c_p >> 3;
                const float* A = &mxs[sE][scn][(e_sl-4)*8];
                const float* B = &mxs[sO][scn][(e_sl-4)*8];
                float4 a0 = *(const float4*)A, aq = *(const float4*)(A+4);
                float4 b0 = *(const float4*)B, bq = *(const float4*)(B+4);
                pv = wreg[0]*a0.x + wreg[1]*b0.x + wreg[2]*a0.y + wreg[3]*b0.y
                   + wreg[4]*a0.z + wreg[5]*b0.z + wreg[6]*a0.w + wreg[7]*b0.w
                   + wreg[8]*aq.x + wreg[9]*bq.x + wreg[10]*aq.y + wreg[11]*bq.y
                   + wreg[12]*aq.z + wreg[13]*bq.z + wreg[14]*aq.w + wreg[15]*bq.w;
            }
            pv += __shfl_xor(pv, 1);
            pv += __shfl_xor(pv, 2);
            pv += __shfl_xor(pv, 4);
            float rm = pv + bhps;
            float ro = __shfl_xor(rm, 8);
            float r0 = e_d ? ro : rm;
            float r1 = e_d ? rm : ro;
            if (e_sl == 0)
                out[(st*BATCH + blockIdx.x*PEDS + c_p)*2 + e_d] = rm;
            if (st < SEQLEN-1) {
                // conv1 col st+6: taps = taus st+6, st+7, st+8(=new rel)
                float2 pa = *(const float2*)&pos[(st+6)&7][c_p][0];
                float2 pb = *(const float2*)&pos[(st+7)&7][c_p][0];
                CONV1_WRITE((st+6)&3, pa.x, pa.y, pb.x, pb.y, r0, r1);
                if (e_sl == 0)
                    pos[st & 7][c_p][e_d] = rm;   // tau st+8; distinct slot from reads
            }
        }
        if (st == SEQLEN-1) break;
        __syncthreads();
        if (wv < 2) CONV2_COL(st + 4);   // reads s1 st+4..st+6 (st+6 just written)
        __syncthreads();
        if (wv >= 2) CONV3_COL(st + 2);  // reads s2 st+2..st+4 (st+4 just written)
        __syncthreads();
    }
}

extern "C" void kernel_launch(void* const* d_in, const int* in_sizes, int n_in,
                              void* d_out, int out_size, void* d_ws, size_t ws_size,
                              hipStream_t stream)
{
    const float* obs = (const float*)d_in[0];
    // d_in[1] last_pos, d_in[2] last_pos_rel: dead state (never reaches output)
    const float* Wse = (const float*)d_in[3];
    const float* bse = (const float*)d_in[4];
    const float* v1  = (const float*)d_in[5];
    const float* g1  = (const float*)d_in[6];
    const float* b1  = (const float*)d_in[7];
    const float* v2  = (const float*)d_in[8];
    const float* g2  = (const float*)d_in[9];
    const float* b2  = (const float*)d_in[10];
    const float* v3  = (const float*)d_in[11];
    const float* g3  = (const float*)d_in[12];
    const float* b3  = (const float*)d_in[13];
    const float* Whp = (const float*)d_in[14];
    const float* bhp = (const float*)d_in[15];
    // d_in[16] seq_start_end: structurally seg = ped>>3 ; d_in[17] seq_len = 12

    enc_main<<<NBLK, 256, 0, stream>>>(obs, Wse, bse, v1, g1, b1, v2, g2, b2,
                                       v3, g3, b3, Whp, bhp, (float*)d_out);
}